// Round 20
// baseline (167.149 us; speedup 1.0000x reference)
//
#include <hip/hip_runtime.h>
#include <hip/hip_fp16.h>
#include <math.h>

#define NB 4
#define NC 96
#define NH 128
#define NW 128
#define HWSZ (NH * NW)          // 16384
#define NK 9
#define AUXC 27                 // 18 offset + 9 mask channels
#define CKK (NC * NK)           // 864
#define WCS_STEP 1280           // shorts per conv27 K-step slab (32 rows x 40)
#define WCS_SHORTS (27 * WCS_STEP)      // 34560
#define WBS_STEP 4096           // shorts per deform K-step slab (96 rows x 40 + pad)
#define WBS_SHORTS (27 * WBS_STEP)      // 110592
#define PIXB (NC * 2)           // 192 bytes per NHWC pixel record (fp16)
#define ZOFF ((unsigned int)(NB * HWSZ * PIXB))   // zero-record byte offset

typedef __attribute__((ext_vector_type(8))) _Float16 f16x8;
typedef __attribute__((ext_vector_type(2))) _Float16 f16x2;
typedef __attribute__((ext_vector_type(4))) float f32x4;

__device__ __forceinline__ unsigned short f16r(float f) {
    return __half_as_ushort(__float2half(f));    // RNE f32->f16 bits
}
__device__ __forceinline__ f16x2 h2bcast(unsigned int bits16) {
    unsigned int u = bits16 | (bits16 << 16);
    union { unsigned int u; f16x2 h; } c; c.u = u;
    return c.h;
}

// async global->LDS, 16B per lane; HW writes wave-uniform base + lane*16.
__device__ __forceinline__ void gload_lds16(const void* g, void* l) {
    __builtin_amdgcn_global_load_lds(
        (const __attribute__((address_space(1))) void*)g,
        (__attribute__((address_space(3))) void*)l, 16, 0, 0);
}

// ---------------------------------------------------------------------------
// Kernel 0: weight prep (fp16 LDS slab images, tap-major K: kk = tap*96+c)
// ---------------------------------------------------------------------------
__global__ __launch_bounds__(256) void prep_weights_kernel(
    const float* __restrict__ offw, const float* __restrict__ modw,
    const float* __restrict__ w,
    unsigned short* __restrict__ wcs, unsigned short* __restrict__ wbs)
{
    int idx = blockIdx.x * 256 + threadIdx.x;
    if (idx < WCS_SHORTS) {
        int st = idx / WCS_STEP;
        int r  = idx - st * WCS_STEP;
        int oc = r / 40;
        int k2 = r - oc * 40;
        unsigned short v = 0;
        if (k2 < 32) {
            int tap = st / 3;
            int c   = (st - 3 * tap) * 32 + k2;
            if (oc < 18)      v = f16r(offw[oc * CKK + c * NK + tap]);
            else if (oc < 27) v = f16r(modw[(oc - 18) * CKK + c * NK + tap]);
        }
        wcs[idx] = v;
    }
    int j = idx - WCS_SHORTS;
    if (j >= 0 && j < WBS_SHORTS) {
        int st = j >> 12;                   // /4096
        int r  = j & 4095;
        int oc = r / 40;
        int k2 = r - oc * 40;
        unsigned short v = 0;
        if (oc < NC && k2 < 32) {
            int tap = st / 3;
            int c   = (st - 3 * tap) * 32 + k2;
            v = f16r(w[oc * CKK + c * NK + tap]);
        }
        wbs[j] = v;
    }
}

// ---------------------------------------------------------------------------
// Kernel 0b: NCHW f32 -> NHWC fp16 transpose + zero-record init. (layer 1)
// ---------------------------------------------------------------------------
__global__ __launch_bounds__(256) void nhwc_kernel(
    const float* __restrict__ in, unsigned short* __restrict__ o)
{
    __shared__ unsigned short tile[64][98];
    int t = threadIdx.x;
    int blk = blockIdx.x;
    int b  = blk >> 8;
    int p0 = (blk & 255) * 64;

    if (blk == 0 && t < NC) o[(size_t)NB * HWSZ * NC + t] = 0;  // zero record

    const float* ib = in + (size_t)b * NC * HWSZ + p0;
#pragma unroll
    for (int r = 0; r < 12; ++r) {
        int e = (r * 256 + t) * 2;
        int c = e >> 6, px = e & 63;
        float2 v = *(const float2*)(ib + c * HWSZ + px);
        tile[px][c]     = f16r(v.x);
        tile[px + 1][c] = f16r(v.y);
    }
    __syncthreads();

    unsigned short* ob = o + ((size_t)b * HWSZ + p0) * NC;
#pragma unroll
    for (int r = 0; r < 12; ++r) {
        int e = (r * 256 + t) * 2;
        int px = e / 96, c = e - px * 96;
        ushort2 u;
        u.x = tile[px][c];
        u.y = tile[px][c + 1];
        *(ushort2*)(ob + e) = u;
    }
}

// ---------------------------------------------------------------------------
// Kernel 0c: fused BN + leakyReLU + NCHW->NHWC fp16 (layer 2 input).
// ---------------------------------------------------------------------------
__global__ __launch_bounds__(256) void nhwcbn_kernel(
    const float* __restrict__ in, const float* __restrict__ sc,
    unsigned short* __restrict__ o)
{
    __shared__ unsigned short tile[64][98];
    int t = threadIdx.x;
    int blk = blockIdx.x;
    int b  = blk >> 8;
    int p0 = (blk & 255) * 64;

    const float* ib = in + (size_t)b * NC * HWSZ + p0;
#pragma unroll
    for (int r = 0; r < 12; ++r) {
        int e = (r * 256 + t) * 2;
        int c = e >> 6, px = e & 63;
        float scale = sc[c], shift = sc[NC + c];
        float2 v = *(const float2*)(ib + c * HWSZ + px);
        float ox = fmaf(scale, v.x, shift); ox = ox >= 0.f ? ox : 0.1f * ox;
        float oy = fmaf(scale, v.y, shift); oy = oy >= 0.f ? oy : 0.1f * oy;
        tile[px][c]     = f16r(ox);
        tile[px + 1][c] = f16r(oy);
    }
    __syncthreads();

    unsigned short* ob = o + ((size_t)b * HWSZ + p0) * NC;
#pragma unroll
    for (int r = 0; r < 12; ++r) {
        int e = (r * 256 + t) * 2;
        int px = e / 96, c = e - px * 96;
        ushort2 u;
        u.x = tile[px][c];
        u.y = tile[px][c + 1];
        *(ushort2*)(ob + e) = u;
    }
}

// ---------------------------------------------------------------------------
// Kernel 1: conv27 MFMA GEMM (fp16), LDS weight slab ring, counted-vmcnt
// barrier: per wave <=1 DMA (issued first, pinned) + 1 sample in flight;
// s_waitcnt vmcnt(1) + raw s_barrier drains ONLY the DMA.
// ---------------------------------------------------------------------------
__global__ __launch_bounds__(512, 4) void conv27_mfma_kernel(
    const unsigned short* __restrict__ xhwc,
    const unsigned short* __restrict__ wcs,    // [27][1280] fp16 slabs
    const float* __restrict__ offb, const float* __restrict__ modb,
    float* __restrict__ aux)
{
    __shared__ unsigned int sOff[NK][66];                // 2376 B
    __shared__ float sRed[4][8][64];                     // 8192 B
    __shared__ unsigned short wr[2][2][WCS_STEP];        // 10240 B ring

    int t = threadIdx.x;
    int bid = blockIdx.x;
    int work = ((bid & 7) << 7) | (bid >> 3);
    int base = work * 64;
    int b = base >> 14;
    int rem0 = base & (HWSZ - 1);
    int y = rem0 >> 7;
    int x0 = rem0 & (NW - 1);

    const int lane15   = t & 15;
    const int g        = (t >> 4) & 3;
    const int wv       = t >> 6;
    const int nt       = wv & 3;
    const int ks       = wv >> 2;
    const int px_local = (nt << 4) | lane15;
    const int g8       = g << 3;
    const int l64      = t & 63;

    auto stageC = [&](int st0, int st1, int slot) {
        if (st0 >= 0 && t < 160)
            gload_lds16((const char*)wcs + (size_t)st0 * (WCS_STEP * 2) + t * 16,
                        (char*)&wr[0][slot][0] + t * 16);
        if (st1 >= 0 && t >= 256 && t < 416)
            gload_lds16((const char*)wcs + (size_t)st1 * (WCS_STEP * 2) + (t - 256) * 16,
                        (char*)&wr[1][slot][0] + (t - 256) * 16);
    };

    stageC(0, 14, 0);

    for (int e = t; e < 576; e += 512) {
        int px = e & 63, k = e >> 6;
        int ky = k / 3, kx = k - 3 * (k / 3);
        int yy = y + ky - 1, xx = x0 + px + kx - 1;
        bool v = (yy >= 0) && (yy < NH) && (xx >= 0) && (xx < NW);
        sOff[k][px] = v ? (unsigned int)(((b << 14) + yy * NW + xx) * PIXB)
                        : ZOFF;
    }
    __syncthreads();   // geometry + first slabs ready (full drain, once)

    const char* pB = (const char*)xhwc;
    auto loadB = [&](int st) -> f16x8 {
        int tap = st / 3;
        int c2  = ((st - 3 * tap) * 32 + g8) * 2;
        return *(const f16x8*)(pB + sOff[tap][px_local] + c2);
    };

    f32x4 acc[2];
    acc[0] = (f32x4){0.f, 0.f, 0.f, 0.f};
    acc[1] = (f32x4){0.f, 0.f, 0.f, 0.f};

    const int stbeg = ks ? 14 : 0;
    const int stend = ks ? 27 : 14;

    f16x8 bfr = loadB(stbeg);

    for (int i = 0; i < 14; ++i) {
        int stc = stbeg + i;
        stageC((i + 1 < 14) ? i + 1 : -1,
               (15 + i < 27) ? 15 + i : -1, (i + 1) & 1);
        __builtin_amdgcn_sched_barrier(0);   // pin DMA issue before sample load
        f16x8 bn = (stc + 1 < stend) ? loadB(stc + 1) : bfr;
        if (stc < stend) {                        // uniform per half
            f16x8 a0 = *(const f16x8*)(&wr[ks][i & 1][lane15 * 40 + g8]);
            f16x8 a1 = *(const f16x8*)(&wr[ks][i & 1][(16 + lane15) * 40 + g8]);
            acc[0] = __builtin_amdgcn_mfma_f32_16x16x32_f16(a0, bfr, acc[0], 0, 0, 0);
            acc[1] = __builtin_amdgcn_mfma_f32_16x16x32_f16(a1, bfr, acc[1], 0, 0, 0);
        }
        asm volatile("s_waitcnt vmcnt(1)" ::: "memory");  // drain DMA only
        __builtin_amdgcn_s_barrier();
        bfr = bn;
    }

    if (ks == 1) {
#pragma unroll
        for (int i = 0; i < 2; ++i)
#pragma unroll
            for (int r = 0; r < 4; ++r)
                sRed[nt][i * 4 + r][l64] = acc[i][r];
    }
    __syncthreads();
    if (ks == 0) {
        float* ap = aux + (size_t)b * AUXC * HWSZ + y * NW + x0 + px_local;
#pragma unroll
        for (int i = 0; i < 2; ++i) {
#pragma unroll
            for (int r = 0; r < 4; ++r) {
                int oc = i * 16 + g * 4 + r;
                float v = acc[i][r] + sRed[nt][i * 4 + r][l64];
                if (oc < 18) {
                    ap[oc * HWSZ] = v + offb[oc];
                } else if (oc < AUXC) {
                    float z = v + modb[oc - 18];
                    ap[oc * HWSZ] = 2.f / (1.f + __expf(-z));
                }
            }
        }
    }
}

// ---------------------------------------------------------------------------
// Kernel 2: deformable sampling + MFMA (fp16), r14 structure, counted-vmcnt
// barrier: per wave 5 VMEM/step issued DMA-first (pinned); vmcnt(4) + raw
// s_barrier drains ONLY the DMA — the 4 sample prefetches stay in flight.
// ---------------------------------------------------------------------------
__global__ __launch_bounds__(512, 4) void deform_mfma_kernel(
    const unsigned short* __restrict__ xhwc,   // [b][yx][c] fp16 (+zero rec)
    const float* __restrict__ aux,             // (B,27,H,W)
    const unsigned short* __restrict__ wbs,    // [27][4096] fp16 slabs
    float* __restrict__ out)                   // (B,C,H,W) pre-BN
{
    __shared__ uint4 sA[NK][NW];               // 18432 B
    __shared__ uint2 sW[NK][NW];               // 9216 B
    __shared__ unsigned short ws[2][WBS_STEP]; // 16384 B weight double-buffer

    int t = threadIdx.x;
    int bid = blockIdx.x;
    int work = ((bid & 7) << 6) | (bid >> 3);  // bijective, 512 wg
    int b = work >> 7;
    int y = work & 127;

    const float* auxb = aux + (size_t)b * AUXC * HWSZ;

    for (int e = t; e < NK * NW; e += 512) {
        int px = e & 127;
        int k  = e >> 7;
        int idx = y * NW + px;
        float offy = auxb[(2 * k) * HWSZ + idx];
        float offx = auxb[(2 * k + 1) * HWSZ + idx];
        float m    = auxb[(18 + k) * HWSZ + idx];
        int ky = k / 3, kx = k - 3 * (k / 3);
        float py  = (float)(y - 1 + ky) + offy;
        float pxf = (float)(px - 1 + kx) + offx;
        float y0f = floorf(py), x0f = floorf(pxf);
        float dy = py - y0f, dx = pxf - x0f;
        int iy0 = (int)y0f, ix0 = (int)x0f;
        int iy1 = iy0 + 1,  ix1 = ix0 + 1;

        bool vy0 = (iy0 >= 0) && (iy0 < NH);
        bool vy1 = (iy1 >= 0) && (iy1 < NH);
        bool vx0 = (ix0 >= 0) && (ix0 < NW);
        bool vx1 = (ix1 >= 0) && (ix1 < NW);
        int cy0 = min(max(iy0, 0), NH - 1);
        int cy1 = min(max(iy1, 0), NH - 1);
        int cx0 = min(max(ix0, 0), NW - 1);
        int cx1 = min(max(ix1, 0), NW - 1);

        float g00 = (1.f - dy) * (1.f - dx) * m; if (!(vy0 && vx0)) g00 = 0.f;
        float g01 = (1.f - dy) * dx * m;         if (!(vy0 && vx1)) g01 = 0.f;
        float g10 = dy * (1.f - dx) * m;         if (!(vy1 && vx0)) g10 = 0.f;
        float g11 = dy * dx * m;                 if (!(vy1 && vx1)) g11 = 0.f;

        uint4 ua;
        ua.x = (unsigned int)(cy0 * NW + cx0) * PIXB;
        ua.y = (unsigned int)(cy0 * NW + cx1) * PIXB;
        ua.z = (unsigned int)(cy1 * NW + cx0) * PIXB;
        ua.w = (unsigned int)(cy1 * NW + cx1) * PIXB;
        uint2 uw;
        uw.x = (unsigned int)f16r(g00) | ((unsigned int)f16r(g01) << 16);
        uw.y = (unsigned int)f16r(g10) | ((unsigned int)f16r(g11) << 16);
        sA[k][px] = ua;
        sW[k][px] = uw;
    }

    gload_lds16((const char*)wbs + (size_t)t * 16, (char*)&ws[0][0] + t * 16);
    __syncthreads();   // geometry + slab 0 (full drain, once)

    f32x4 acc[6];
#pragma unroll
    for (int i = 0; i < 6; ++i) acc[i] = (f32x4){0.f, 0.f, 0.f, 0.f};

    const int lane15   = t & 15;
    const int g        = (t >> 4) & 3;
    const int wv       = t >> 6;                // n-tile
    const int px_local = (wv << 4) | lane15;
    const int g8       = g << 3;

    const char* pB = (const char*)(xhwc + (size_t)b * HWSZ * NC);

    uint4 ga = sA[0][px_local];
    uint2 gw = sW[0][px_local];
    f16x8 v0 = *(const f16x8*)(pB + ga.x + (g8 << 1));
    f16x8 v1 = *(const f16x8*)(pB + ga.y + (g8 << 1));
    f16x8 v2 = *(const f16x8*)(pB + ga.z + (g8 << 1));
    f16x8 v3 = *(const f16x8*)(pB + ga.w + (g8 << 1));

    int buf = 0;
    for (int st = 0; st < 27; ++st) {
        bool more = (st + 1 < 27);
        uint4 gaN; uint2 gwN;
        f16x8 n0, n1, n2, n3;
        if (more) {
            gload_lds16((const char*)wbs + (size_t)(st + 1) * (WBS_STEP * 2) + t * 16,
                        (char*)&ws[buf ^ 1][0] + t * 16);
            __builtin_amdgcn_sched_barrier(0);   // pin DMA before sample loads
            int kn  = (st + 1) / 3;
            int c2n = ((st + 1 - 3 * kn) * 32 + g8) * 2;
            gaN = sA[kn][px_local];
            gwN = sW[kn][px_local];
            n0 = *(const f16x8*)(pB + gaN.x + c2n);
            n1 = *(const f16x8*)(pB + gaN.y + c2n);
            n2 = *(const f16x8*)(pB + gaN.z + c2n);
            n3 = *(const f16x8*)(pB + gaN.w + c2n);
        }

        f16x8 afr[6];
#pragma unroll
        for (int i = 0; i < 6; ++i)
            afr[i] = *(const f16x8*)(&ws[buf][(i * 16 + lane15) * 40 + g8]);

        // packed fp16 combine: per dword 4 pk-FMAs, no unpack/repack
        f16x2 w00 = h2bcast(gw.x & 0xffffu);
        f16x2 w01 = h2bcast(gw.x >> 16);
        f16x2 w10 = h2bcast(gw.y & 0xffffu);
        f16x2 w11 = h2bcast(gw.y >> 16);
        union U8 { f16x8 v; f16x2 d[4]; } A, B, C, D, R;
        A.v = v0; B.v = v1; C.v = v2; D.v = v3;
#pragma unroll
        for (int dd = 0; dd < 4; ++dd) {
            f16x2 s = A.d[dd] * w00;
            s = B.d[dd] * w01 + s;
            s = C.d[dd] * w10 + s;
            s = D.d[dd] * w11 + s;
            R.d[dd] = s;
        }
        f16x8 bfr = R.v;

#pragma unroll
        for (int i = 0; i < 6; ++i)
            acc[i] = __builtin_amdgcn_mfma_f32_16x16x32_f16(afr[i], bfr, acc[i], 0, 0, 0);

        if (more) {
            asm volatile("s_waitcnt vmcnt(4)" ::: "memory");  // drain DMA only
            __builtin_amdgcn_s_barrier();
            ga = gaN; gw = gwN; v0 = n0; v1 = n1; v2 = n2; v3 = n3;
            buf ^= 1;
        }
    }

    float* ob = out + (size_t)b * NC * HWSZ + y * NW + px_local;
#pragma unroll
    for (int i = 0; i < 6; ++i) {
        int row0 = i * 16 + g * 4;
#pragma unroll
        for (int r = 0; r < 4; ++r)
            ob[(row0 + r) * HWSZ] = acc[i][r];
    }
}

// ---------------------------------------------------------------------------
// Kernel 3a: per-(b,c) partial sums.  Kernel 3b: finalize scale/shift.
// ---------------------------------------------------------------------------
__global__ __launch_bounds__(256) void bnstats_kernel(
    const float* __restrict__ h, float* __restrict__ part)
{
    int bc = blockIdx.x;
    const float4* p = (const float4*)(h + (size_t)bc * HWSZ);
    float s = 0.f, s2 = 0.f;
    for (int i = threadIdx.x; i < HWSZ / 4; i += 256) {
        float4 v = p[i];
        s  += v.x + v.y + v.z + v.w;
        s2 += v.x * v.x + v.y * v.y + v.z * v.z + v.w * v.w;
    }
#pragma unroll
    for (int o = 32; o > 0; o >>= 1) {
        s  += __shfl_down(s, o);
        s2 += __shfl_down(s2, o);
    }
    __shared__ float red[8];
    int wv = threadIdx.x >> 6, ln = threadIdx.x & 63;
    if (ln == 0) { red[wv] = s; red[4 + wv] = s2; }
    __syncthreads();
    if (threadIdx.x == 0) {
        part[bc]            = red[0] + red[1] + red[2] + red[3];
        part[NB * NC + bc]  = red[4] + red[5] + red[6] + red[7];
    }
}

__global__ __launch_bounds__(128) void bnfinalize_kernel(
    const float* __restrict__ part, const float* __restrict__ g,
    const float* __restrict__ bt, float* __restrict__ sc)
{
    int c = threadIdx.x;
    if (c >= NC) return;
    float s = 0.f, s2 = 0.f;
#pragma unroll
    for (int b = 0; b < NB; ++b) {
        s  += part[b * NC + c];
        s2 += part[NB * NC + b * NC + c];
    }
    const float inv_n = 1.f / (float)(NB * HWSZ);
    float mean = s * inv_n;
    float var  = s2 * inv_n - mean * mean;
    float scale = g[c] * rsqrtf(var + 1e-5f);
    sc[c] = scale;
    sc[NC + c] = bt[c] - mean * scale;
}

// ---------------------------------------------------------------------------
// Kernel 5: out = x + BN(out_raw) in place
// ---------------------------------------------------------------------------
__global__ __launch_bounds__(256) void final_kernel(
    float* __restrict__ out, const float* __restrict__ x,
    const float* __restrict__ sc)
{
    const int n4 = NB * NC * HWSZ / 4;
    for (int i = blockIdx.x * 256 + threadIdx.x; i < n4; i += gridDim.x * 256) {
        int c = (i >> 12) % NC;
        float scale = sc[c], shift = sc[NC + c];
        float4 v = ((const float4*)out)[i];
        float4 xv = ((const float4*)x)[i];
        float4 o;
        o.x = xv.x + fmaf(scale, v.x, shift);
        o.y = xv.y + fmaf(scale, v.y, shift);
        o.z = xv.z + fmaf(scale, v.z, shift);
        o.w = xv.w + fmaf(scale, v.w, shift);
        ((float4*)out)[i] = o;
    }
}

// ---------------------------------------------------------------------------
extern "C" void kernel_launch(void* const* d_in, const int* in_sizes, int n_in,
                              void* d_out, int out_size, void* d_ws, size_t ws_size,
                              hipStream_t stream)
{
    const float* x        = (const float*)d_in[0];
    const float* d1_off_w = (const float*)d_in[1];
    const float* d1_off_b = (const float*)d_in[2];
    const float* d1_mod_w = (const float*)d_in[3];
    const float* d1_mod_b = (const float*)d_in[4];
    const float* d1_w     = (const float*)d_in[5];
    const float* d2_off_w = (const float*)d_in[6];
    const float* d2_off_b = (const float*)d_in[7];
    const float* d2_mod_w = (const float*)d_in[8];
    const float* d2_mod_b = (const float*)d_in[9];
    const float* d2_w     = (const float*)d_in[10];
    const float* bn_g     = (const float*)d_in[11];
    const float* bn_b     = (const float*)d_in[12];
    float* out = (float*)d_out;

    // ws layout (floats): h1 | aux | wcs | wbs | sc | part | xhwc(+zero rec)
    const size_t nImg = (size_t)NB * NC * HWSZ;
    float* h1   = (float*)d_ws;
    float* aux  = h1   + nImg;
    unsigned short* wcs = (unsigned short*)(aux + (size_t)NB * AUXC * HWSZ);
    unsigned short* wbs = wcs + WCS_SHORTS;
    float* sc   = (float*)(wbs + WBS_SHORTS);
    float* part = sc + 2 * NC;
    unsigned short* xhwc = (unsigned short*)(part + 2 * NB * NC);

    const int npix = NB * HWSZ;                       // 65536
    const int prep_blocks = (WCS_SHORTS + WBS_SHORTS + 255) / 256;

    // ---- layer 1 ----
    prep_weights_kernel<<<prep_blocks, 256, 0, stream>>>(d1_off_w, d1_mod_w, d1_w, wcs, wbs);
    nhwc_kernel<<<npix / 64, 256, 0, stream>>>(x, xhwc);
    conv27_mfma_kernel<<<npix / 64, 512, 0, stream>>>(xhwc, wcs, d1_off_b, d1_mod_b, aux);
    deform_mfma_kernel<<<NB * NH, 512, 0, stream>>>(xhwc, aux, wbs, h1);
    bnstats_kernel<<<NB * NC, 256, 0, stream>>>(h1, part);
    bnfinalize_kernel<<<1, 128, 0, stream>>>(part, bn_g, bn_b, sc);

    // ---- layer 2 ----
    prep_weights_kernel<<<prep_blocks, 256, 0, stream>>>(d2_off_w, d2_mod_w, d2_w, wcs, wbs);
    nhwcbn_kernel<<<npix / 64, 256, 0, stream>>>(h1, sc, xhwc);
    conv27_mfma_kernel<<<npix / 64, 512, 0, stream>>>(xhwc, wcs, d2_off_b, d2_mod_b, aux);
    deform_mfma_kernel<<<NB * NH, 512, 0, stream>>>(xhwc, aux, wbs, out);
    bnstats_kernel<<<NB * NC, 256, 0, stream>>>(out, part);
    bnfinalize_kernel<<<1, 128, 0, stream>>>(part, bn_g, bn_b, sc);
    final_kernel<<<2048, 256, 0, stream>>>(out, x, sc);
}

// Round 21
// 163.283 us; speedup vs baseline: 1.0237x; 1.0237x over previous
//
#include <hip/hip_runtime.h>
#include <hip/hip_fp16.h>
#include <math.h>

#define NB 4
#define NC 96
#define NH 128
#define NW 128
#define HWSZ (NH * NW)          // 16384
#define NK 9
#define AUXC 27                 // 18 offset + 9 mask channels
#define CKK (NC * NK)           // 864
#define WCS_STEP 1280           // shorts per conv27 K-step slab (32 rows x 40)
#define WCS_SHORTS (27 * WCS_STEP)      // 34560
#define WBS_STEP 4096           // shorts per deform K-step slab (96 rows x 40 + pad)
#define WBS_SHORTS (27 * WBS_STEP)      // 110592
#define PIXB (NC * 2)           // 192 bytes per NHWC pixel record (fp16)
#define ZOFF ((unsigned int)(NB * HWSZ * PIXB))   // zero-record byte offset

typedef __attribute__((ext_vector_type(8))) _Float16 f16x8;
typedef __attribute__((ext_vector_type(2))) _Float16 f16x2;
typedef __attribute__((ext_vector_type(4))) float f32x4;

__device__ __forceinline__ unsigned short f16r(float f) {
    return __half_as_ushort(__float2half(f));    // RNE f32->f16 bits
}
__device__ __forceinline__ f16x2 h2bcast(unsigned int bits16) {
    unsigned int u = bits16 | (bits16 << 16);
    union { unsigned int u; f16x2 h; } c; c.u = u;
    return c.h;
}

// async global->LDS, 16B per lane; HW writes wave-uniform base + lane*16.
__device__ __forceinline__ void gload_lds16(const void* g, void* l) {
    __builtin_amdgcn_global_load_lds(
        (const __attribute__((address_space(1))) void*)g,
        (__attribute__((address_space(3))) void*)l, 16, 0, 0);
}

// ---------------------------------------------------------------------------
// Kernel 0: weight prep (fp16 LDS slab images, tap-major K: kk = tap*96+c)
//   wcs[st*1280 + oc*40 + k2]  conv27 (oc<18 offw, 18..26 modw, else 0)
//   wbs[st*4096 + oc*40 + k2]  deform (96 rows, 40-short padded)
// ---------------------------------------------------------------------------
__global__ __launch_bounds__(256) void prep_weights_kernel(
    const float* __restrict__ offw, const float* __restrict__ modw,
    const float* __restrict__ w,
    unsigned short* __restrict__ wcs, unsigned short* __restrict__ wbs)
{
    int idx = blockIdx.x * 256 + threadIdx.x;
    if (idx < WCS_SHORTS) {
        int st = idx / WCS_STEP;
        int r  = idx - st * WCS_STEP;
        int oc = r / 40;
        int k2 = r - oc * 40;
        unsigned short v = 0;
        if (k2 < 32) {
            int tap = st / 3;
            int c   = (st - 3 * tap) * 32 + k2;
            if (oc < 18)      v = f16r(offw[oc * CKK + c * NK + tap]);
            else if (oc < 27) v = f16r(modw[(oc - 18) * CKK + c * NK + tap]);
        }
        wcs[idx] = v;
    }
    int j = idx - WCS_SHORTS;
    if (j >= 0 && j < WBS_SHORTS) {
        int st = j >> 12;                   // /4096
        int r  = j & 4095;
        int oc = r / 40;
        int k2 = r - oc * 40;
        unsigned short v = 0;
        if (oc < NC && k2 < 32) {
            int tap = st / 3;
            int c   = (st - 3 * tap) * 32 + k2;
            v = f16r(w[oc * CKK + c * NK + tap]);
        }
        wbs[j] = v;
    }
}

// ---------------------------------------------------------------------------
// Kernel 0b: NCHW f32 -> NHWC fp16 transpose + zero-record init. (layer 1)
// ---------------------------------------------------------------------------
__global__ __launch_bounds__(256) void nhwc_kernel(
    const float* __restrict__ in, unsigned short* __restrict__ o)
{
    __shared__ unsigned short tile[64][98];
    int t = threadIdx.x;
    int blk = blockIdx.x;
    int b  = blk >> 8;
    int p0 = (blk & 255) * 64;

    if (blk == 0 && t < NC) o[(size_t)NB * HWSZ * NC + t] = 0;  // zero record

    const float* ib = in + (size_t)b * NC * HWSZ + p0;
#pragma unroll
    for (int r = 0; r < 12; ++r) {
        int e = (r * 256 + t) * 2;
        int c = e >> 6, px = e & 63;
        float2 v = *(const float2*)(ib + c * HWSZ + px);
        tile[px][c]     = f16r(v.x);
        tile[px + 1][c] = f16r(v.y);
    }
    __syncthreads();

    unsigned short* ob = o + ((size_t)b * HWSZ + p0) * NC;
#pragma unroll
    for (int r = 0; r < 12; ++r) {
        int e = (r * 256 + t) * 2;
        int px = e / 96, c = e - px * 96;
        ushort2 u;
        u.x = tile[px][c];
        u.y = tile[px][c + 1];
        *(ushort2*)(ob + e) = u;
    }
}

// ---------------------------------------------------------------------------
// Kernel 0c: fused BN + leakyReLU + NCHW->NHWC fp16 (layer 2 input).
// ---------------------------------------------------------------------------
__global__ __launch_bounds__(256) void nhwcbn_kernel(
    const float* __restrict__ in, const float* __restrict__ sc,
    unsigned short* __restrict__ o)
{
    __shared__ unsigned short tile[64][98];
    int t = threadIdx.x;
    int blk = blockIdx.x;
    int b  = blk >> 8;
    int p0 = (blk & 255) * 64;

    const float* ib = in + (size_t)b * NC * HWSZ + p0;
#pragma unroll
    for (int r = 0; r < 12; ++r) {
        int e = (r * 256 + t) * 2;
        int c = e >> 6, px = e & 63;
        float scale = sc[c], shift = sc[NC + c];
        float2 v = *(const float2*)(ib + c * HWSZ + px);
        float ox = fmaf(scale, v.x, shift); ox = ox >= 0.f ? ox : 0.1f * ox;
        float oy = fmaf(scale, v.y, shift); oy = oy >= 0.f ? oy : 0.1f * oy;
        tile[px][c]     = f16r(ox);
        tile[px + 1][c] = f16r(oy);
    }
    __syncthreads();

    unsigned short* ob = o + ((size_t)b * HWSZ + p0) * NC;
#pragma unroll
    for (int r = 0; r < 12; ++r) {
        int e = (r * 256 + t) * 2;
        int px = e / 96, c = e - px * 96;
        ushort2 u;
        u.x = tile[px][c];
        u.y = tile[px][c + 1];
        *(ushort2*)(ob + e) = u;
    }
}

// ---------------------------------------------------------------------------
// Kernel 1: conv27 MFMA GEMM (fp16) with LDS weight slab ring.
// Structure identical to r14; dtype fp16, MFMA 16x16x32_f16.
// ---------------------------------------------------------------------------
__global__ __launch_bounds__(512, 4) void conv27_mfma_kernel(
    const unsigned short* __restrict__ xhwc,
    const unsigned short* __restrict__ wcs,    // [27][1280] fp16 slabs
    const float* __restrict__ offb, const float* __restrict__ modb,
    float* __restrict__ aux)
{
    __shared__ unsigned int sOff[NK][66];                // 2376 B
    __shared__ float sRed[4][8][64];                     // 8192 B
    __shared__ unsigned short wr[2][2][WCS_STEP];        // 10240 B ring

    int t = threadIdx.x;
    int bid = blockIdx.x;
    int work = ((bid & 7) << 7) | (bid >> 3);
    int base = work * 64;
    int b = base >> 14;
    int rem0 = base & (HWSZ - 1);
    int y = rem0 >> 7;
    int x0 = rem0 & (NW - 1);

    const int lane15   = t & 15;
    const int g        = (t >> 4) & 3;
    const int wv       = t >> 6;
    const int nt       = wv & 3;
    const int ks       = wv >> 2;
    const int px_local = (nt << 4) | lane15;
    const int g8       = g << 3;
    const int l64      = t & 63;

    auto stageC = [&](int st0, int st1, int slot) {
        if (st0 >= 0 && t < 160)
            gload_lds16((const char*)wcs + (size_t)st0 * (WCS_STEP * 2) + t * 16,
                        (char*)&wr[0][slot][0] + t * 16);
        if (st1 >= 0 && t >= 256 && t < 416)
            gload_lds16((const char*)wcs + (size_t)st1 * (WCS_STEP * 2) + (t - 256) * 16,
                        (char*)&wr[1][slot][0] + (t - 256) * 16);
    };

    stageC(0, 14, 0);

    for (int e = t; e < 576; e += 512) {
        int px = e & 63, k = e >> 6;
        int ky = k / 3, kx = k - 3 * (k / 3);
        int yy = y + ky - 1, xx = x0 + px + kx - 1;
        bool v = (yy >= 0) && (yy < NH) && (xx >= 0) && (xx < NW);
        sOff[k][px] = v ? (unsigned int)(((b << 14) + yy * NW + xx) * PIXB)
                        : ZOFF;
    }
    __syncthreads();   // geometry + first slabs ready

    const char* pB = (const char*)xhwc;
    auto loadB = [&](int st) -> f16x8 {
        int tap = st / 3;
        int c2  = ((st - 3 * tap) * 32 + g8) * 2;
        return *(const f16x8*)(pB + sOff[tap][px_local] + c2);
    };

    f32x4 acc[2];
    acc[0] = (f32x4){0.f, 0.f, 0.f, 0.f};
    acc[1] = (f32x4){0.f, 0.f, 0.f, 0.f};

    const int stbeg = ks ? 14 : 0;
    const int stend = ks ? 27 : 14;

    f16x8 bfr = loadB(stbeg);

    for (int i = 0; i < 14; ++i) {
        int stc = stbeg + i;
        stageC((i + 1 < 14) ? i + 1 : -1,
               (15 + i < 27) ? 15 + i : -1, (i + 1) & 1);
        f16x8 bn = (stc + 1 < stend) ? loadB(stc + 1) : bfr;
        if (stc < stend) {                        // uniform per half
            f16x8 a0 = *(const f16x8*)(&wr[ks][i & 1][lane15 * 40 + g8]);
            f16x8 a1 = *(const f16x8*)(&wr[ks][i & 1][(16 + lane15) * 40 + g8]);
            acc[0] = __builtin_amdgcn_mfma_f32_16x16x32_f16(a0, bfr, acc[0], 0, 0, 0);
            acc[1] = __builtin_amdgcn_mfma_f32_16x16x32_f16(a1, bfr, acc[1], 0, 0, 0);
        }
        __syncthreads();
        bfr = bn;
    }

    if (ks == 1) {
#pragma unroll
        for (int i = 0; i < 2; ++i)
#pragma unroll
            for (int r = 0; r < 4; ++r)
                sRed[nt][i * 4 + r][l64] = acc[i][r];
    }
    __syncthreads();
    if (ks == 0) {
        float* ap = aux + (size_t)b * AUXC * HWSZ + y * NW + x0 + px_local;
#pragma unroll
        for (int i = 0; i < 2; ++i) {
#pragma unroll
            for (int r = 0; r < 4; ++r) {
                int oc = i * 16 + g * 4 + r;
                float v = acc[i][r] + sRed[nt][i * 4 + r][l64];
                if (oc < 18) {
                    ap[oc * HWSZ] = v + offb[oc];
                } else if (oc < AUXC) {
                    float z = v + modb[oc - 18];
                    ap[oc * HWSZ] = 2.f / (1.f + __expf(-z));
                }
            }
        }
    }
}

// ---------------------------------------------------------------------------
// Kernel 2: deformable sampling + MFMA (fp16), r14 structure.
// Combine uses packed fp16 FMA (v_pk_fma_f16): 16 pk-FMA replace 32 unpack
// + 32 scalar FMA + 4 cvt_pk. Result dwords ARE the MFMA B-fragment.
// ---------------------------------------------------------------------------
__global__ __launch_bounds__(512, 4) void deform_mfma_kernel(
    const unsigned short* __restrict__ xhwc,   // [b][yx][c] fp16 (+zero rec)
    const float* __restrict__ aux,             // (B,27,H,W)
    const unsigned short* __restrict__ wbs,    // [27][4096] fp16 slabs
    float* __restrict__ out)                   // (B,C,H,W) pre-BN
{
    __shared__ uint4 sA[NK][NW];               // 18432 B
    __shared__ uint2 sW[NK][NW];               // 9216 B
    __shared__ unsigned short ws[2][WBS_STEP]; // 16384 B weight double-buffer

    int t = threadIdx.x;
    int bid = blockIdx.x;
    int work = ((bid & 7) << 6) | (bid >> 3);  // bijective, 512 wg
    int b = work >> 7;
    int y = work & 127;

    const float* auxb = aux + (size_t)b * AUXC * HWSZ;

    for (int e = t; e < NK * NW; e += 512) {
        int px = e & 127;
        int k  = e >> 7;
        int idx = y * NW + px;
        float offy = auxb[(2 * k) * HWSZ + idx];
        float offx = auxb[(2 * k + 1) * HWSZ + idx];
        float m    = auxb[(18 + k) * HWSZ + idx];
        int ky = k / 3, kx = k - 3 * (k / 3);
        float py  = (float)(y - 1 + ky) + offy;
        float pxf = (float)(px - 1 + kx) + offx;
        float y0f = floorf(py), x0f = floorf(pxf);
        float dy = py - y0f, dx = pxf - x0f;
        int iy0 = (int)y0f, ix0 = (int)x0f;
        int iy1 = iy0 + 1,  ix1 = ix0 + 1;

        bool vy0 = (iy0 >= 0) && (iy0 < NH);
        bool vy1 = (iy1 >= 0) && (iy1 < NH);
        bool vx0 = (ix0 >= 0) && (ix0 < NW);
        bool vx1 = (ix1 >= 0) && (ix1 < NW);
        int cy0 = min(max(iy0, 0), NH - 1);
        int cy1 = min(max(iy1, 0), NH - 1);
        int cx0 = min(max(ix0, 0), NW - 1);
        int cx1 = min(max(ix1, 0), NW - 1);

        float g00 = (1.f - dy) * (1.f - dx) * m; if (!(vy0 && vx0)) g00 = 0.f;
        float g01 = (1.f - dy) * dx * m;         if (!(vy0 && vx1)) g01 = 0.f;
        float g10 = dy * (1.f - dx) * m;         if (!(vy1 && vx0)) g10 = 0.f;
        float g11 = dy * dx * m;                 if (!(vy1 && vx1)) g11 = 0.f;

        uint4 ua;
        ua.x = (unsigned int)(cy0 * NW + cx0) * PIXB;
        ua.y = (unsigned int)(cy0 * NW + cx1) * PIXB;
        ua.z = (unsigned int)(cy1 * NW + cx0) * PIXB;
        ua.w = (unsigned int)(cy1 * NW + cx1) * PIXB;
        uint2 uw;
        uw.x = (unsigned int)f16r(g00) | ((unsigned int)f16r(g01) << 16);
        uw.y = (unsigned int)f16r(g10) | ((unsigned int)f16r(g11) << 16);
        sA[k][px] = ua;
        sW[k][px] = uw;
    }

    gload_lds16((const char*)wbs + (size_t)t * 16, (char*)&ws[0][0] + t * 16);
    __syncthreads();

    f32x4 acc[6];
#pragma unroll
    for (int i = 0; i < 6; ++i) acc[i] = (f32x4){0.f, 0.f, 0.f, 0.f};

    const int lane15   = t & 15;
    const int g        = (t >> 4) & 3;
    const int wv       = t >> 6;                // n-tile
    const int px_local = (wv << 4) | lane15;
    const int g8       = g << 3;

    const char* pB = (const char*)(xhwc + (size_t)b * HWSZ * NC);

    uint4 ga = sA[0][px_local];
    uint2 gw = sW[0][px_local];
    f16x8 v0 = *(const f16x8*)(pB + ga.x + (g8 << 1));
    f16x8 v1 = *(const f16x8*)(pB + ga.y + (g8 << 1));
    f16x8 v2 = *(const f16x8*)(pB + ga.z + (g8 << 1));
    f16x8 v3 = *(const f16x8*)(pB + ga.w + (g8 << 1));

    int buf = 0;
    for (int st = 0; st < 27; ++st) {
        bool more = (st + 1 < 27);
        uint4 gaN; uint2 gwN;
        f16x8 n0, n1, n2, n3;
        if (more) {
            gload_lds16((const char*)wbs + (size_t)(st + 1) * (WBS_STEP * 2) + t * 16,
                        (char*)&ws[buf ^ 1][0] + t * 16);
            int kn  = (st + 1) / 3;
            int c2n = ((st + 1 - 3 * kn) * 32 + g8) * 2;
            gaN = sA[kn][px_local];
            gwN = sW[kn][px_local];
            n0 = *(const f16x8*)(pB + gaN.x + c2n);
            n1 = *(const f16x8*)(pB + gaN.y + c2n);
            n2 = *(const f16x8*)(pB + gaN.z + c2n);
            n3 = *(const f16x8*)(pB + gaN.w + c2n);
        }

        f16x8 afr[6];
#pragma unroll
        for (int i = 0; i < 6; ++i)
            afr[i] = *(const f16x8*)(&ws[buf][(i * 16 + lane15) * 40 + g8]);

        // packed fp16 combine: per dword 4 pk-FMAs, no unpack/repack
        f16x2 w00 = h2bcast(gw.x & 0xffffu);
        f16x2 w01 = h2bcast(gw.x >> 16);
        f16x2 w10 = h2bcast(gw.y & 0xffffu);
        f16x2 w11 = h2bcast(gw.y >> 16);
        union U8 { f16x8 v; f16x2 d[4]; } A, B, C, D, R;
        A.v = v0; B.v = v1; C.v = v2; D.v = v3;
#pragma unroll
        for (int dd = 0; dd < 4; ++dd) {
            f16x2 s = A.d[dd] * w00;
            s = B.d[dd] * w01 + s;
            s = C.d[dd] * w10 + s;
            s = D.d[dd] * w11 + s;
            R.d[dd] = s;
        }
        f16x8 bfr = R.v;

#pragma unroll
        for (int i = 0; i < 6; ++i)
            acc[i] = __builtin_amdgcn_mfma_f32_16x16x32_f16(afr[i], bfr, acc[i], 0, 0, 0);

        if (more) {
            __syncthreads();
            ga = gaN; gw = gwN; v0 = n0; v1 = n1; v2 = n2; v3 = n3;
            buf ^= 1;
        }
    }

    float* ob = out + (size_t)b * NC * HWSZ + y * NW + px_local;
#pragma unroll
    for (int i = 0; i < 6; ++i) {
        int row0 = i * 16 + g * 4;
#pragma unroll
        for (int r = 0; r < 4; ++r)
            ob[(row0 + r) * HWSZ] = acc[i][r];
    }
}

// ---------------------------------------------------------------------------
// Kernel 3a: per-(b,c) partial sums.  Kernel 3b: finalize scale/shift.
// ---------------------------------------------------------------------------
__global__ __launch_bounds__(256) void bnstats_kernel(
    const float* __restrict__ h, float* __restrict__ part)
{
    int bc = blockIdx.x;
    const float4* p = (const float4*)(h + (size_t)bc * HWSZ);
    float s = 0.f, s2 = 0.f;
    for (int i = threadIdx.x; i < HWSZ / 4; i += 256) {
        float4 v = p[i];
        s  += v.x + v.y + v.z + v.w;
        s2 += v.x * v.x + v.y * v.y + v.z * v.z + v.w * v.w;
    }
#pragma unroll
    for (int o = 32; o > 0; o >>= 1) {
        s  += __shfl_down(s, o);
        s2 += __shfl_down(s2, o);
    }
    __shared__ float red[8];
    int wv = threadIdx.x >> 6, ln = threadIdx.x & 63;
    if (ln == 0) { red[wv] = s; red[4 + wv] = s2; }
    __syncthreads();
    if (threadIdx.x == 0) {
        part[bc]            = red[0] + red[1] + red[2] + red[3];
        part[NB * NC + bc]  = red[4] + red[5] + red[6] + red[7];
    }
}

__global__ __launch_bounds__(128) void bnfinalize_kernel(
    const float* __restrict__ part, const float* __restrict__ g,
    const float* __restrict__ bt, float* __restrict__ sc)
{
    int c = threadIdx.x;
    if (c >= NC) return;
    float s = 0.f, s2 = 0.f;
#pragma unroll
    for (int b = 0; b < NB; ++b) {
        s  += part[b * NC + c];
        s2 += part[NB * NC + b * NC + c];
    }
    const float inv_n = 1.f / (float)(NB * HWSZ);
    float mean = s * inv_n;
    float var  = s2 * inv_n - mean * mean;
    float scale = g[c] * rsqrtf(var + 1e-5f);
    sc[c] = scale;
    sc[NC + c] = bt[c] - mean * scale;
}

// ---------------------------------------------------------------------------
// Kernel 5: out = x + BN(out_raw) in place
// ---------------------------------------------------------------------------
__global__ __launch_bounds__(256) void final_kernel(
    float* __restrict__ out, const float* __restrict__ x,
    const float* __restrict__ sc)
{
    const int n4 = NB * NC * HWSZ / 4;
    for (int i = blockIdx.x * 256 + threadIdx.x; i < n4; i += gridDim.x * 256) {
        int c = (i >> 12) % NC;
        float scale = sc[c], shift = sc[NC + c];
        float4 v = ((const float4*)out)[i];
        float4 xv = ((const float4*)x)[i];
        float4 o;
        o.x = xv.x + fmaf(scale, v.x, shift);
        o.y = xv.y + fmaf(scale, v.y, shift);
        o.z = xv.z + fmaf(scale, v.z, shift);
        o.w = xv.w + fmaf(scale, v.w, shift);
        ((float4*)out)[i] = o;
    }
}

// ---------------------------------------------------------------------------
extern "C" void kernel_launch(void* const* d_in, const int* in_sizes, int n_in,
                              void* d_out, int out_size, void* d_ws, size_t ws_size,
                              hipStream_t stream)
{
    const float* x        = (const float*)d_in[0];
    const float* d1_off_w = (const float*)d_in[1];
    const float* d1_off_b = (const float*)d_in[2];
    const float* d1_mod_w = (const float*)d_in[3];
    const float* d1_mod_b = (const float*)d_in[4];
    const float* d1_w     = (const float*)d_in[5];
    const float* d2_off_w = (const float*)d_in[6];
    const float* d2_off_b = (const float*)d_in[7];
    const float* d2_mod_w = (const float*)d_in[8];
    const float* d2_mod_b = (const float*)d_in[9];
    const float* d2_w     = (const float*)d_in[10];
    const float* bn_g     = (const float*)d_in[11];
    const float* bn_b     = (const float*)d_in[12];
    float* out = (float*)d_out;

    // ws layout (floats): h1 | aux | wcs | wbs | sc | part | xhwc(+zero rec)
    const size_t nImg = (size_t)NB * NC * HWSZ;
    float* h1   = (float*)d_ws;
    float* aux  = h1   + nImg;
    unsigned short* wcs = (unsigned short*)(aux + (size_t)NB * AUXC * HWSZ);
    unsigned short* wbs = wcs + WCS_SHORTS;
    float* sc   = (float*)(wbs + WBS_SHORTS);
    float* part = sc + 2 * NC;
    unsigned short* xhwc = (unsigned short*)(part + 2 * NB * NC);

    const int npix = NB * HWSZ;                       // 65536
    const int prep_blocks = (WCS_SHORTS + WBS_SHORTS + 255) / 256;

    // ---- layer 1 ----
    prep_weights_kernel<<<prep_blocks, 256, 0, stream>>>(d1_off_w, d1_mod_w, d1_w, wcs, wbs);
    nhwc_kernel<<<npix / 64, 256, 0, stream>>>(x, xhwc);
    conv27_mfma_kernel<<<npix / 64, 512, 0, stream>>>(xhwc, wcs, d1_off_b, d1_mod_b, aux);
    deform_mfma_kernel<<<NB * NH, 512, 0, stream>>>(xhwc, aux, wbs, h1);
    bnstats_kernel<<<NB * NC, 256, 0, stream>>>(h1, part);
    bnfinalize_kernel<<<1, 128, 0, stream>>>(part, bn_g, bn_b, sc);

    // ---- layer 2 ----
    prep_weights_kernel<<<prep_blocks, 256, 0, stream>>>(d2_off_w, d2_mod_w, d2_w, wcs, wbs);
    nhwcbn_kernel<<<npix / 64, 256, 0, stream>>>(h1, sc, xhwc);
    conv27_mfma_kernel<<<npix / 64, 512, 0, stream>>>(xhwc, wcs, d2_off_b, d2_mod_b, aux);
    deform_mfma_kernel<<<NB * NH, 512, 0, stream>>>(xhwc, aux, wbs, out);
    bnstats_kernel<<<NB * NC, 256, 0, stream>>>(out, part);
    bnfinalize_kernel<<<1, 128, 0, stream>>>(part, bn_g, bn_b, sc);
    final_kernel<<<2048, 256, 0, stream>>>(out, x, sc);
}